// Round 3
// baseline (242.353 us; speedup 1.0000x reference)
//
#include <hip/hip_runtime.h>
#include <hip/hip_bf16.h>
#include <math.h>

#define NPOS 32768      // 32*32*32
#define CCH  128
#define C3   384
#define CF   512

typedef __attribute__((ext_vector_type(8))) short short8;
typedef __attribute__((ext_vector_type(4))) float f32x4;

__device__ inline float bf2f(unsigned short u) {
    union { unsigned int i; float f; } x; x.i = ((unsigned int)u) << 16; return x.f;
}
__device__ inline unsigned short f2bf(float f) {
    union { float f; unsigned int i; } x; x.f = f;
    unsigned int r = x.i + 0x7FFFu + ((x.i >> 16) & 1u);   // round-nearest-even
    return (unsigned short)(r >> 16);
}

// ---------------------------------------------------------------------------
// bf16 MFMA GEMM: out[M,Nout] = A(M,K) * B(Nout,K)^T + bias (+gelu)(+residual)
// 128x128 tile, BK=32, 256 thr = 4 waves (2x2 of 64x64), 16x16x32 bf16 MFMA.
// ---------------------------------------------------------------------------
template<bool GELU, bool RES, bool WF32, bool WBF>
__global__ __launch_bounds__(256) void gemm_mfma(
    const unsigned short* __restrict__ A, const unsigned short* __restrict__ B,
    const float* __restrict__ bias, const unsigned short* __restrict__ res,
    float* __restrict__ outf, unsigned short* __restrict__ outb,
    int M, int Nout, int K)
{
    __shared__ alignas(16) unsigned short As[128 * 40];
    __shared__ alignas(16) unsigned short Bs[128 * 40];

    const int tid  = threadIdx.x;
    const int lane = tid & 63;
    const int wave = tid >> 6;
    const int wm = wave & 1, wn = wave >> 1;
    const int row0 = blockIdx.y * 128;
    const int col0 = blockIdx.x * 128;

    const f32x4 fzero = {0.f, 0.f, 0.f, 0.f};
    f32x4 acc[4][4];
    #pragma unroll
    for (int i = 0; i < 4; ++i)
        #pragma unroll
        for (int j = 0; j < 4; ++j) acc[i][j] = fzero;

    const int lr = lane & 15;
    const int lk = (lane >> 4) * 8;

    for (int kt = 0; kt < K; kt += 32) {
        #pragma unroll
        for (int it = 0; it < 2; ++it) {
            const int c = tid + it * 256;
            const int r = c >> 2;
            const int p = (c & 3) * 8;
            *(uint4*)&As[r * 40 + p] = *(const uint4*)&A[(size_t)(row0 + r) * K + kt + p];
            *(uint4*)&Bs[r * 40 + p] = *(const uint4*)&B[(size_t)(col0 + r) * K + kt + p];
        }
        __syncthreads();
        short8 af[4], bfr[4];
        #pragma unroll
        for (int i = 0; i < 4; ++i)
            af[i]  = *(const short8*)&As[(wm * 64 + i * 16 + lr) * 40 + lk];
        #pragma unroll
        for (int j = 0; j < 4; ++j)
            bfr[j] = *(const short8*)&Bs[(wn * 64 + j * 16 + lr) * 40 + lk];
        #pragma unroll
        for (int i = 0; i < 4; ++i)
            #pragma unroll
            for (int j = 0; j < 4; ++j)
                acc[i][j] = __builtin_amdgcn_mfma_f32_16x16x32_bf16(
                                af[i], bfr[j], acc[i][j], 0, 0, 0);
        __syncthreads();
    }

    const int gr0 = row0 + wm * 64 + (lane >> 4) * 4;
    const int gc0 = col0 + wn * 64 + lr;
    #pragma unroll
    for (int j = 0; j < 4; ++j) {
        const int gc = gc0 + j * 16;
        const float bv = bias[gc];
        #pragma unroll
        for (int i = 0; i < 4; ++i) {
            #pragma unroll
            for (int r = 0; r < 4; ++r) {
                const int gr = gr0 + i * 16 + r;
                float v = acc[i][j][r] + bv;
                if (GELU) {
                    const float g = 0.7978845608028654f * (v + 0.044715f * v * v * v);
                    const float e = __expf(2.f * g);
                    v = v * (e / (e + 1.f));
                }
                if (RES)  v += bf2f(res[(size_t)gr * Nout + gc]);
                if (WF32) outf[(size_t)gr * Nout + gc] = v;
                if (WBF)  outb[(size_t)gr * Nout + gc] = f2bf(v);
            }
        }
    }
}

// ---------------------------------------------------------------------------
// Tiled neighborhood attention: block = (one z-line of 32 queries) x (1 head)
// grid (1024 hw-lines, 8 heads), 256 threads.
// Stages k/v for the 3x3x32 neighbor union (288 pos x 16 ch) in LDS as f32.
// ---------------------------------------------------------------------------
__global__ __launch_bounds__(256) void attn_tiled(
    const unsigned short* __restrict__ qkv, const float* __restrict__ rpb,
    unsigned short* __restrict__ out)
{
    __shared__ float ks[288 * 18];     // stride 18 spreads banks, keeps f2 align
    __shared__ float vs[288 * 18];
    __shared__ float qs[32 * 16];
    __shared__ float logits[32 * 28];
    __shared__ float rpbs[125];

    const int t  = threadIdx.x;
    const int bx = blockIdx.x;
    const int h  = blockIdx.y;
    const int w0 = bx & 31, h0 = bx >> 5;
    const int n0 = (h0 << 10) + (w0 << 5);
    const int sh0 = min(max(h0 - 1, 0), 29);
    const int sw0 = min(max(w0 - 1, 0), 29);
    const int rh_off = sh0 - h0 + 2;
    const int rw_off = sw0 - w0 + 2;

    // ---- stage q-line (32 pos x 16 ch) and rpb slice
    if (t < 64) {
        const int pos = t >> 1, part = t & 1;
        uint4 raw = *(const uint4*)&qkv[(size_t)(n0 + pos) * C3 + h * 16 + part * 8];
        const unsigned short* s = (const unsigned short*)&raw;
        float* d = &qs[pos * 16 + part * 8];
        #pragma unroll
        for (int i = 0; i < 8; ++i) d[i] = bf2f(s[i]);
    } else if (t < 192) {
        const int i = t - 64;
        if (i < 125) rpbs[i] = rpb[h * 125 + i];
    }
    // ---- stage k/v: 288 pos x 16 ch, 4 uint4-chunks per pos (k-lo,k-hi,v-lo,v-hi)
    for (int c = t; c < 1152; c += 256) {
        const int p = c >> 2, part = c & 3;
        const int ihw = p >> 5, z = p & 31;
        const int ih = (ihw * 11) >> 5;          // ihw/3 for ihw<32
        const int iw = ihw - 3 * ih;
        const int n = ((sh0 + ih) << 10) + ((sw0 + iw) << 5) + z;
        uint4 raw = *(const uint4*)&qkv[(size_t)n * C3 + CCH + (part >> 1) * CCH + h * 16 + (part & 1) * 8];
        const unsigned short* s = (const unsigned short*)&raw;
        float* d = ((part < 2) ? ks : vs) + p * 18 + (part & 1) * 8;
        #pragma unroll
        for (int i = 0; i < 8; ++i) d[i] = bf2f(s[i]);
    }
    __syncthreads();

    // ---- QK^T + rpb : 8 threads per query, 27 logits
    {
        const int q = t >> 3, j = t & 7;
        const int sz = min(max(q - 1, 0), 29);
        const int rz_off = sz - q + 2;
        for (int kk = j; kk < 27; kk += 8) {
            const int ihw = (kk * 11) >> 5;      // kk/3
            const int dz  = kk - 3 * ihw;
            const int ih  = (ihw * 11) >> 5;     // ihw/3
            const int iw  = ihw - 3 * ih;
            const int p   = ihw * 32 + sz + dz;
            float a = 0.f;
            #pragma unroll
            for (int d2 = 0; d2 < 8; ++d2) {
                const float2 qv = *(const float2*)&qs[q * 16 + d2 * 2];
                const float2 kv = *(const float2*)&ks[p * 18 + d2 * 2];
                a += qv.x * kv.x + qv.y * kv.y;
            }
            const int bidx = ((ih + rh_off) * 5 + (iw + rw_off)) * 5 + (dz + rz_off);
            logits[q * 28 + kk] = a * 0.25f + rpbs[bidx];
        }
    }
    __syncthreads();

    // ---- softmax: one thread per query
    if (t < 32) {
        float mx = -1e30f;
        #pragma unroll
        for (int kk = 0; kk < 27; ++kk) mx = fmaxf(mx, logits[t * 28 + kk]);
        float s = 0.f;
        #pragma unroll
        for (int kk = 0; kk < 27; ++kk) {
            const float e = __expf(logits[t * 28 + kk] - mx);
            logits[t * 28 + kk] = e; s += e;
        }
        const float inv = 1.f / s;
        #pragma unroll
        for (int kk = 0; kk < 27; ++kk) logits[t * 28 + kk] *= inv;
    }
    __syncthreads();

    // ---- PV: thread = (query, dim-pair)
    {
        const int q = t >> 3, d2 = t & 7;
        const int sz = min(max(q - 1, 0), 29);
        float ax = 0.f, ay = 0.f;
        #pragma unroll
        for (int kk = 0; kk < 27; ++kk) {
            const int p = (kk / 3) * 32 + sz + (kk % 3);   // compile-time kk
            const float w = logits[q * 28 + kk];
            const float2 vv = *(const float2*)&vs[p * 18 + d2 * 2];
            ax += w * vv.x; ay += w * vv.y;
        }
        const unsigned int o = ((unsigned int)f2bf(ay) << 16) | (unsigned int)f2bf(ax);
        *(unsigned int*)&out[(size_t)(n0 + q) * CCH + h * 16 + d2 * 2] = o;
    }
}

// ---------------------------------------------------------------------------
// helpers
// ---------------------------------------------------------------------------
__global__ __launch_bounds__(128) void stats_kernel(
    const float* __restrict__ a, float* __restrict__ stats)
{
    const int c = threadIdx.x;
    const int r0 = blockIdx.x * 128;
    float s = 0.f, sq = 0.f;
    for (int r = 0; r < 128; ++r) {
        const float v = a[(size_t)(r0 + r) * CCH + c];
        s += v; sq += v * v;
    }
    atomicAdd(&stats[c], s);
    atomicAdd(&stats[CCH + c], sq);
}

// fused: zero stats + convert all four weight matrices fp32->bf16
__global__ __launch_bounds__(256) void prep_kernel(
    const float* __restrict__ wq, const float* __restrict__ wp,
    const float* __restrict__ w1, const float* __restrict__ w2,
    unsigned short* __restrict__ wq_b, unsigned short* __restrict__ wp_b,
    unsigned short* __restrict__ w1_b, unsigned short* __restrict__ w2_b,
    float* __restrict__ stats)
{
    const int i = blockIdx.x * 256 + threadIdx.x;   // float4 index, < 49152
    if (blockIdx.x == 0) {
        stats[threadIdx.x] = 0.f;
        stats[threadIdx.x + 256] = 0.f;
    }
    const float* src; unsigned short* dst; int off;
    if (i < 12288)      { src = wq; dst = wq_b; off = i; }
    else if (i < 16384) { src = wp; dst = wp_b; off = i - 12288; }
    else if (i < 32768) { src = w1; dst = w1_b; off = i - 16384; }
    else                { src = w2; dst = w2_b; off = i - 32768; }
    const float4 v = ((const float4*)src)[off];
    ushort4 o;
    o.x = f2bf(v.x); o.y = f2bf(v.y); o.z = f2bf(v.z); o.w = f2bf(v.w);
    ((ushort4*)dst)[off] = o;
}

// normalize (N,128) fp32 -> bf16
__global__ __launch_bounds__(256) void norm_apply_bf(
    const float* __restrict__ a, const float* __restrict__ stats,
    unsigned short* __restrict__ o)
{
    const int i = blockIdx.x * 256 + threadIdx.x;
    const int c0 = (i * 4) & (CCH - 1);
    const float4 v = ((const float4*)a)[i];
    const float invN = 1.f / (float)NPOS;
    ushort4 r;
    #pragma unroll
    for (int j = 0; j < 4; ++j) {
        const int c = c0 + j;
        const float m = stats[c] * invN;
        const float var = stats[CCH + c] * invN - m * m;
        const float rs = rsqrtf(var + 1e-5f);
        (&r.x)[j] = f2bf(((&v.x)[j] - m) * rs);
    }
    *(ushort4*)&o[(size_t)i * 4] = r;
}

// normalize + transpose (N,C) fp32 -> (C,N) fp32 output
__global__ void norm_transpose_kernel(
    const float* __restrict__ t, const float* __restrict__ stats,
    float* __restrict__ out)
{
    __shared__ float tile[32][33];
    const int n0 = blockIdx.x * 32;
    const int c0 = blockIdx.y * 32;
    const int tx = threadIdx.x;
    const int ty = threadIdx.y;
    for (int i = ty; i < 32; i += 8)
        tile[i][tx] = t[(size_t)(n0 + i) * CCH + c0 + tx];
    __syncthreads();
    const float invN = 1.f / (float)NPOS;
    for (int i = ty; i < 32; i += 8) {
        const int c = c0 + i;
        const float m = stats[c] * invN;
        const float var = stats[CCH + c] * invN - m * m;
        const float rs = rsqrtf(var + 1e-5f);
        out[(size_t)c * NPOS + n0 + tx] = (tile[tx][i] - m) * rs;
    }
}

// transpose x (C,N) fp32 -> (N,C) bf16
__global__ __launch_bounds__(256) void transpose_x_kernel(
    const float* __restrict__ x, unsigned short* __restrict__ xt)
{
    __shared__ float tile[32][33];
    const int n0 = blockIdx.x * 32;
    const int c0 = blockIdx.y * 32;
    const int tx = threadIdx.x & 31;
    const int ty = threadIdx.x >> 5;
    for (int i = ty; i < 32; i += 8)
        tile[i][tx] = x[(size_t)(c0 + i) * NPOS + n0 + tx];
    __syncthreads();
    for (int i = ty; i < 32; i += 8)
        xt[(size_t)(n0 + i) * CCH + c0 + tx] = f2bf(tile[tx][i]);
}

// ---------------------------------------------------------------------------
extern "C" void kernel_launch(void* const* d_in, const int* in_sizes, int n_in,
                              void* d_out, int out_size, void* d_ws, size_t ws_size,
                              hipStream_t stream)
{
    const float* x      = (const float*)d_in[0];   // (128, 32768) = (C, N)
    const float* w_qkv  = (const float*)d_in[1];
    const float* b_qkv  = (const float*)d_in[2];
    const float* rpb    = (const float*)d_in[3];
    const float* w_proj = (const float*)d_in[4];
    const float* b_proj = (const float*)d_in[5];
    const float* w_ffn1 = (const float*)d_in[6];
    const float* b_ffn1 = (const float*)d_in[7];
    const float* w_ffn2 = (const float*)d_in[8];
    const float* b_ffn2 = (const float*)d_in[9];
    float* out = (float*)d_out;

    char* ws = (char*)d_ws;
    unsigned short* xt_bf    = (unsigned short*)(ws + 0);          // 8.39 MB
    unsigned short* qkv_bf   = (unsigned short*)(ws + 8388608);    // 25.2 MB
    unsigned short* ffn1_bf  = (unsigned short*)(ws + 0);          // 33.6 MB (reuse)
    unsigned short* attnO_bf = (unsigned short*)(ws + 33554432);   // 8.39 MB
    float*          x5       = (float*)(ws + 41943040);            // 16.8 MB
    unsigned short* x5n_bf   = (unsigned short*)(ws + 58720256);   // 8.39 MB
    float*          tbuf     = (float*)(ws + 67108864);            // 16.8 MB
    unsigned short* wqkv_bf  = (unsigned short*)(ws + 83886080);
    unsigned short* wproj_bf = (unsigned short*)(ws + 83984384);
    unsigned short* wffn1_bf = (unsigned short*)(ws + 84017152);
    unsigned short* wffn2_bf = (unsigned short*)(ws + 84148224);
    float*          stats    = (float*)(ws + 84279296);

    // 0) fused prep: zero stats + weight conversions; transpose-convert x
    prep_kernel<<<192, 256, 0, stream>>>(w_qkv, w_proj, w_ffn1, w_ffn2,
                                         wqkv_bf, wproj_bf, wffn1_bf, wffn2_bf, stats);
    transpose_x_kernel<<<dim3(NPOS / 32, CCH / 32), 256, 0, stream>>>(x, xt_bf);

    // 1) qkv = xt @ w_qkv^T + b_qkv   (bf16 out)
    gemm_mfma<false, false, false, true><<<dim3(C3 / 128, NPOS / 128), 256, 0, stream>>>(
        xt_bf, wqkv_bf, b_qkv, nullptr, nullptr, qkv_bf, NPOS, C3, CCH);

    // 2) tiled neighborhood attention
    attn_tiled<<<dim3(1024, 8), 256, 0, stream>>>(qkv_bf, rpb, attnO_bf);

    // 3) x5 = attnO @ w_proj^T + b_proj  (fp32 out)
    gemm_mfma<false, false, true, false><<<dim3(1, NPOS / 128), 256, 0, stream>>>(
        attnO_bf, wproj_bf, b_proj, nullptr, x5, nullptr, NPOS, CCH, CCH);

    // 4) instance norm #1
    stats_kernel<<<256, 128, 0, stream>>>(x5, stats);
    norm_apply_bf<<<(NPOS * CCH / 4) / 256, 256, 0, stream>>>(x5, stats, x5n_bf);

    // 5) ffn1 = gelu(x5n @ w_ffn1^T + b_ffn1)  (bf16 out)
    gemm_mfma<true, false, false, true><<<dim3(CF / 128, NPOS / 128), 256, 0, stream>>>(
        x5n_bf, wffn1_bf, b_ffn1, nullptr, nullptr, ffn1_bf, NPOS, CF, CCH);

    // 6) t = x5n + ffn1 @ w_ffn2^T + b_ffn2  (fp32 out)
    gemm_mfma<false, true, true, false><<<dim3(1, NPOS / 128), 256, 0, stream>>>(
        ffn1_bf, wffn2_bf, b_ffn2, x5n_bf, tbuf, nullptr, NPOS, CCH, CF);

    // 7) instance norm #2 + transpose to (C,N)
    stats_kernel<<<256, 128, 0, stream>>>(tbuf, stats + 256);
    norm_transpose_kernel<<<dim3(NPOS / 32, CCH / 32), dim3(32, 8), 0, stream>>>(
        tbuf, stats + 256, out);
}

// Round 4
// 212.724 us; speedup vs baseline: 1.1393x; 1.1393x over previous
//
#include <hip/hip_runtime.h>
#include <hip/hip_bf16.h>
#include <math.h>

#define NPOS 32768      // 32*32*32
#define CCH  128
#define C3   384
#define CF   512

typedef __attribute__((ext_vector_type(8))) short short8;
typedef __attribute__((ext_vector_type(4))) float f32x4;

__device__ inline float bf2f(unsigned short u) {
    union { unsigned int i; float f; } x; x.i = ((unsigned int)u) << 16; return x.f;
}
__device__ inline unsigned short f2bf(float f) {
    union { float f; unsigned int i; } x; x.f = f;
    unsigned int r = x.i + 0x7FFFu + ((x.i >> 16) & 1u);   // round-nearest-even
    return (unsigned short)(r >> 16);
}
__device__ inline float lo_bf(unsigned int u) {
    union { unsigned int i; float f; } x; x.i = u << 16; return x.f;
}
__device__ inline float hi_bf(unsigned int u) {
    union { unsigned int i; float f; } x; x.i = u & 0xffff0000u; return x.f;
}

// ---------------------------------------------------------------------------
// bf16 MFMA GEMM: out[M,Nout] = A(M,K) * B(Nout,K)^T + bias (+gelu)(+residual)
// 128x128 tile, BK=32, 256 thr = 4 waves (2x2 of 64x64), 16x16x32 bf16 MFMA.
// ---------------------------------------------------------------------------
template<bool GELU, bool RES, bool WF32, bool WBF>
__global__ __launch_bounds__(256) void gemm_mfma(
    const unsigned short* __restrict__ A, const unsigned short* __restrict__ B,
    const float* __restrict__ bias, const unsigned short* __restrict__ res,
    float* __restrict__ outf, unsigned short* __restrict__ outb,
    int M, int Nout, int K)
{
    __shared__ alignas(16) unsigned short As[128 * 40];
    __shared__ alignas(16) unsigned short Bs[128 * 40];

    const int tid  = threadIdx.x;
    const int lane = tid & 63;
    const int wave = tid >> 6;
    const int wm = wave & 1, wn = wave >> 1;
    const int row0 = blockIdx.y * 128;
    const int col0 = blockIdx.x * 128;

    const f32x4 fzero = {0.f, 0.f, 0.f, 0.f};
    f32x4 acc[4][4];
    #pragma unroll
    for (int i = 0; i < 4; ++i)
        #pragma unroll
        for (int j = 0; j < 4; ++j) acc[i][j] = fzero;

    const int lr = lane & 15;
    const int lk = (lane >> 4) * 8;

    for (int kt = 0; kt < K; kt += 32) {
        #pragma unroll
        for (int it = 0; it < 2; ++it) {
            const int c = tid + it * 256;
            const int r = c >> 2;
            const int p = (c & 3) * 8;
            *(uint4*)&As[r * 40 + p] = *(const uint4*)&A[(size_t)(row0 + r) * K + kt + p];
            *(uint4*)&Bs[r * 40 + p] = *(const uint4*)&B[(size_t)(col0 + r) * K + kt + p];
        }
        __syncthreads();
        short8 af[4], bfr[4];
        #pragma unroll
        for (int i = 0; i < 4; ++i)
            af[i]  = *(const short8*)&As[(wm * 64 + i * 16 + lr) * 40 + lk];
        #pragma unroll
        for (int j = 0; j < 4; ++j)
            bfr[j] = *(const short8*)&Bs[(wn * 64 + j * 16 + lr) * 40 + lk];
        #pragma unroll
        for (int i = 0; i < 4; ++i)
            #pragma unroll
            for (int j = 0; j < 4; ++j)
                acc[i][j] = __builtin_amdgcn_mfma_f32_16x16x32_bf16(
                                af[i], bfr[j], acc[i][j], 0, 0, 0);
        __syncthreads();
    }

    const int gr0 = row0 + wm * 64 + (lane >> 4) * 4;
    const int gc0 = col0 + wn * 64 + lr;
    #pragma unroll
    for (int j = 0; j < 4; ++j) {
        const int gc = gc0 + j * 16;
        const float bv = bias[gc];
        #pragma unroll
        for (int i = 0; i < 4; ++i) {
            #pragma unroll
            for (int r = 0; r < 4; ++r) {
                const int gr = gr0 + i * 16 + r;
                float v = acc[i][j][r] + bv;
                if (GELU) {
                    const float g = 0.7978845608028654f * (v + 0.044715f * v * v * v);
                    const float e = __expf(2.f * g);
                    v = v * (e / (e + 1.f));
                }
                if (RES)  v += bf2f(res[(size_t)gr * Nout + gc]);
                if (WF32) outf[(size_t)gr * Nout + gc] = v;
                if (WBF)  outb[(size_t)gr * Nout + gc] = f2bf(v);
            }
        }
    }
}

// ---------------------------------------------------------------------------
// Tiled neighborhood attention: block = (one z-line of 32 queries) x (1 head)
// grid (1024 swizzled hw-lines, 8 heads), 256 threads.
// k/v staged as PACKED bf16 pairs (u32), stride 8 u32/pos -> 2-way-max banks.
// ---------------------------------------------------------------------------
__global__ __launch_bounds__(256) void attn_tiled(
    const unsigned short* __restrict__ qkv, const float* __restrict__ rpb,
    unsigned short* __restrict__ out)
{
    __shared__ unsigned int ksu[288 * 8];   // 9216 B, [pos][8 bf16-pairs]
    __shared__ unsigned int vsu[288 * 8];   // 9216 B
    __shared__ unsigned int qsu[32 * 8];    // 1024 B
    __shared__ float logits[32 * 29];       // 3712 B (29 coprime 32)
    __shared__ float rpbs[125];

    const int t  = threadIdx.x;
    // XCD swizzle: 128 contiguous lines per XCD (~4MB union = one L2)
    const int line = ((blockIdx.x & 7) << 7) + (blockIdx.x >> 3);
    const int h  = blockIdx.y;
    const int w0 = line & 31, h0 = line >> 5;
    const int n0 = (h0 << 10) + (w0 << 5);
    const int sh0 = min(max(h0 - 1, 0), 29);
    const int sw0 = min(max(w0 - 1, 0), 29);
    const int rh_off = sh0 - h0 + 2;
    const int rw_off = sw0 - w0 + 2;

    // ---- stage q-line (32 pos x 16 ch) packed + rpb slice
    if (t < 64) {
        const int pos = t >> 1, part = t & 1;
        const uint4 raw = *(const uint4*)&qkv[(size_t)(n0 + pos) * C3 + h * 16 + part * 8];
        *(uint4*)&qsu[pos * 8 + part * 4] = raw;
    } else if (t < 192) {
        const int i = t - 64;
        if (i < 125) rpbs[i] = rpb[h * 125 + i];
    }
    // ---- stage k/v: 288 pos, 4 x 16B chunks per pos (k-lo,k-hi,v-lo,v-hi)
    for (int c = t; c < 1152; c += 256) {
        const int p = c >> 2, part = c & 3;
        const int ihw = p >> 5, z = p & 31;
        const int ih = (ihw * 11) >> 5;          // ihw/3
        const int iw = ihw - 3 * ih;
        const int n = ((sh0 + ih) << 10) + ((sw0 + iw) << 5) + z;
        const uint4 raw = *(const uint4*)&qkv[(size_t)n * C3 + CCH + (part >> 1) * CCH
                                              + h * 16 + (part & 1) * 8];
        unsigned int* d = ((part < 2) ? ksu : vsu) + p * 8 + (part & 1) * 4;
        *(uint4*)d = raw;
    }
    __syncthreads();

    // ---- QK^T + rpb : thread = (query, j), 27 logits over j-strided kk
    {
        const int q = t >> 3, j = t & 7;
        const int sz = min(max(q - 1, 0), 29);
        const int rz_off = sz - q + 2;
        float qf[16];
        #pragma unroll
        for (int d2 = 0; d2 < 8; ++d2) {
            const unsigned int u = qsu[q * 8 + d2];
            qf[2 * d2] = lo_bf(u); qf[2 * d2 + 1] = hi_bf(u);
        }
        for (int kk = j; kk < 27; kk += 8) {
            const int ihw = kk / 3, dz = kk - 3 * ihw;
            const int ih = ihw / 3,  iw = ihw - 3 * ih;
            const int p = ihw * 32 + sz + dz;
            float a = 0.f;
            #pragma unroll
            for (int d2 = 0; d2 < 8; ++d2) {
                const unsigned int u = ksu[p * 8 + d2];
                a += qf[2 * d2] * lo_bf(u) + qf[2 * d2 + 1] * hi_bf(u);
            }
            const int bidx = ((ih + rh_off) * 5 + (iw + rw_off)) * 5 + (dz + rz_off);
            logits[q * 29 + kk] = a * 0.25f + rpbs[bidx];
        }
    }
    __syncthreads();

    // ---- softmax: one thread per query (stride 29 -> conflict-free)
    if (t < 32) {
        float mx = -1e30f;
        #pragma unroll
        for (int kk = 0; kk < 27; ++kk) mx = fmaxf(mx, logits[t * 29 + kk]);
        float s = 0.f;
        #pragma unroll
        for (int kk = 0; kk < 27; ++kk) {
            const float e = __expf(logits[t * 29 + kk] - mx);
            logits[t * 29 + kk] = e; s += e;
        }
        const float inv = 1.f / s;
        #pragma unroll
        for (int kk = 0; kk < 27; ++kk) logits[t * 29 + kk] *= inv;
    }
    __syncthreads();

    // ---- PV: thread = (query, dim-pair); v banks = exactly 2-way (free)
    {
        const int q = t >> 3, d2 = t & 7;
        const int sz = min(max(q - 1, 0), 29);
        float ax = 0.f, ay = 0.f;
        #pragma unroll
        for (int kk = 0; kk < 27; ++kk) {
            const int p = (kk / 3) * 32 + sz + (kk % 3);   // kk compile-time
            const float w = logits[q * 29 + kk];           // broadcast across d2
            const unsigned int u = vsu[p * 8 + d2];
            ax += w * lo_bf(u); ay += w * hi_bf(u);
        }
        const unsigned int o = ((unsigned int)f2bf(ay) << 16) | (unsigned int)f2bf(ax);
        *(unsigned int*)&out[(size_t)(n0 + q) * CCH + h * 16 + d2 * 2] = o;
    }
}

// ---------------------------------------------------------------------------
// helpers
// ---------------------------------------------------------------------------
__global__ __launch_bounds__(128) void stats_kernel(
    const float* __restrict__ a, float* __restrict__ stats)
{
    const int c = threadIdx.x;
    const int r0 = blockIdx.x * 128;
    float s = 0.f, sq = 0.f;
    for (int r = 0; r < 128; ++r) {
        const float v = a[(size_t)(r0 + r) * CCH + c];
        s += v; sq += v * v;
    }
    atomicAdd(&stats[c], s);
    atomicAdd(&stats[CCH + c], sq);
}

// fused: zero stats + convert all four weight matrices fp32->bf16
__global__ __launch_bounds__(256) void prep_kernel(
    const float* __restrict__ wq, const float* __restrict__ wp,
    const float* __restrict__ w1, const float* __restrict__ w2,
    unsigned short* __restrict__ wq_b, unsigned short* __restrict__ wp_b,
    unsigned short* __restrict__ w1_b, unsigned short* __restrict__ w2_b,
    float* __restrict__ stats)
{
    const int i = blockIdx.x * 256 + threadIdx.x;
    if (blockIdx.x == 0) {
        stats[threadIdx.x] = 0.f;
        stats[threadIdx.x + 256] = 0.f;
    }
    const float* src; unsigned short* dst; int off;
    if (i < 12288)      { src = wq; dst = wq_b; off = i; }
    else if (i < 16384) { src = wp; dst = wp_b; off = i - 12288; }
    else if (i < 32768) { src = w1; dst = w1_b; off = i - 16384; }
    else                { src = w2; dst = w2_b; off = i - 32768; }
    const float4 v = ((const float4*)src)[off];
    ushort4 o;
    o.x = f2bf(v.x); o.y = f2bf(v.y); o.z = f2bf(v.z); o.w = f2bf(v.w);
    ((ushort4*)dst)[off] = o;
}

// normalize (N,128) fp32 -> bf16
__global__ __launch_bounds__(256) void norm_apply_bf(
    const float* __restrict__ a, const float* __restrict__ stats,
    unsigned short* __restrict__ o)
{
    const int i = blockIdx.x * 256 + threadIdx.x;
    const int c0 = (i * 4) & (CCH - 1);
    const float4 v = ((const float4*)a)[i];
    const float invN = 1.f / (float)NPOS;
    ushort4 r;
    #pragma unroll
    for (int j = 0; j < 4; ++j) {
        const int c = c0 + j;
        const float m = stats[c] * invN;
        const float var = stats[CCH + c] * invN - m * m;
        const float rs = rsqrtf(var + 1e-5f);
        (&r.x)[j] = f2bf(((&v.x)[j] - m) * rs);
    }
    *(ushort4*)&o[(size_t)i * 4] = r;
}

// normalize + transpose (N,C) fp32 -> (C,N) fp32 output
__global__ void norm_transpose_kernel(
    const float* __restrict__ t, const float* __restrict__ stats,
    float* __restrict__ out)
{
    __shared__ float tile[32][33];
    const int n0 = blockIdx.x * 32;
    const int c0 = blockIdx.y * 32;
    const int tx = threadIdx.x;
    const int ty = threadIdx.y;
    for (int i = ty; i < 32; i += 8)
        tile[i][tx] = t[(size_t)(n0 + i) * CCH + c0 + tx];
    __syncthreads();
    const float invN = 1.f / (float)NPOS;
    for (int i = ty; i < 32; i += 8) {
        const int c = c0 + i;
        const float m = stats[c] * invN;
        const float var = stats[CCH + c] * invN - m * m;
        const float rs = rsqrtf(var + 1e-5f);
        out[(size_t)c * NPOS + n0 + tx] = (tile[tx][i] - m) * rs;
    }
}

// transpose x (C,N) fp32 -> (N,C) bf16
__global__ __launch_bounds__(256) void transpose_x_kernel(
    const float* __restrict__ x, unsigned short* __restrict__ xt)
{
    __shared__ float tile[32][33];
    const int n0 = blockIdx.x * 32;
    const int c0 = blockIdx.y * 32;
    const int tx = threadIdx.x & 31;
    const int ty = threadIdx.x >> 5;
    for (int i = ty; i < 32; i += 8)
        tile[i][tx] = x[(size_t)(c0 + i) * NPOS + n0 + tx];
    __syncthreads();
    for (int i = ty; i < 32; i += 8)
        xt[(size_t)(n0 + i) * CCH + c0 + tx] = f2bf(tile[tx][i]);
}

// ---------------------------------------------------------------------------
extern "C" void kernel_launch(void* const* d_in, const int* in_sizes, int n_in,
                              void* d_out, int out_size, void* d_ws, size_t ws_size,
                              hipStream_t stream)
{
    const float* x      = (const float*)d_in[0];   // (128, 32768) = (C, N)
    const float* w_qkv  = (const float*)d_in[1];
    const float* b_qkv  = (const float*)d_in[2];
    const float* rpb    = (const float*)d_in[3];
    const float* w_proj = (const float*)d_in[4];
    const float* b_proj = (const float*)d_in[5];
    const float* w_ffn1 = (const float*)d_in[6];
    const float* b_ffn1 = (const float*)d_in[7];
    const float* w_ffn2 = (const float*)d_in[8];
    const float* b_ffn2 = (const float*)d_in[9];
    float* out = (float*)d_out;

    char* ws = (char*)d_ws;
    unsigned short* xt_bf    = (unsigned short*)(ws + 0);          // 8.39 MB
    unsigned short* qkv_bf   = (unsigned short*)(ws + 8388608);    // 25.2 MB
    unsigned short* ffn1_bf  = (unsigned short*)(ws + 0);          // 33.6 MB (reuse)
    unsigned short* attnO_bf = (unsigned short*)(ws + 33554432);   // 8.39 MB
    float*          x5       = (float*)(ws + 41943040);            // 16.8 MB
    unsigned short* x5n_bf   = (unsigned short*)(ws + 58720256);   // 8.39 MB
    float*          tbuf     = (float*)(ws + 67108864);            // 16.8 MB
    unsigned short* wqkv_bf  = (unsigned short*)(ws + 83886080);
    unsigned short* wproj_bf = (unsigned short*)(ws + 83984384);
    unsigned short* wffn1_bf = (unsigned short*)(ws + 84017152);
    unsigned short* wffn2_bf = (unsigned short*)(ws + 84148224);
    float*          stats    = (float*)(ws + 84279296);

    // 0) fused prep + transpose-convert x
    prep_kernel<<<192, 256, 0, stream>>>(w_qkv, w_proj, w_ffn1, w_ffn2,
                                         wqkv_bf, wproj_bf, wffn1_bf, wffn2_bf, stats);
    transpose_x_kernel<<<dim3(NPOS / 32, CCH / 32), 256, 0, stream>>>(x, xt_bf);

    // 1) qkv = xt @ w_qkv^T + b_qkv   (bf16 out)
    gemm_mfma<false, false, false, true><<<dim3(C3 / 128, NPOS / 128), 256, 0, stream>>>(
        xt_bf, wqkv_bf, b_qkv, nullptr, nullptr, qkv_bf, NPOS, C3, CCH);

    // 2) tiled neighborhood attention
    attn_tiled<<<dim3(1024, 8), 256, 0, stream>>>(qkv_bf, rpb, attnO_bf);

    // 3) x5 = attnO @ w_proj^T + b_proj  (fp32 out)
    gemm_mfma<false, false, true, false><<<dim3(1, NPOS / 128), 256, 0, stream>>>(
        attnO_bf, wproj_bf, b_proj, nullptr, x5, nullptr, NPOS, CCH, CCH);

    // 4) instance norm #1
    stats_kernel<<<256, 128, 0, stream>>>(x5, stats);
    norm_apply_bf<<<(NPOS * CCH / 4) / 256, 256, 0, stream>>>(x5, stats, x5n_bf);

    // 5) ffn1 = gelu(x5n @ w_ffn1^T + b_ffn1)  (bf16 out)
    gemm_mfma<true, false, false, true><<<dim3(CF / 128, NPOS / 128), 256, 0, stream>>>(
        x5n_bf, wffn1_bf, b_ffn1, nullptr, nullptr, ffn1_bf, NPOS, CF, CCH);

    // 6) t = x5n + ffn1 @ w_ffn2^T + b_ffn2  (fp32 out)
    gemm_mfma<false, true, true, false><<<dim3(1, NPOS / 128), 256, 0, stream>>>(
        ffn1_bf, wffn2_bf, b_ffn2, x5n_bf, tbuf, nullptr, NPOS, CCH, CF);

    // 7) instance norm #2 + transpose to (C,N)
    stats_kernel<<<256, 128, 0, stream>>>(tbuf, stats + 256);
    norm_transpose_kernel<<<dim3(NPOS / 32, CCH / 32), dim3(32, 8), 0, stream>>>(
        tbuf, stats + 256, out);
}